// Round 11
// baseline (134.650 us; speedup 1.0000x reference)
//
#include <hip/hip_runtime.h>

// Problem constants
constexpr int B_ = 32, C_ = 64, H_ = 64, W_ = 64, K_ = 1024;
constexpr int NTOT = B_ * C_ * H_ * W_;          // 8388608 elements of input1/quantized
constexpr int NSP  = B_ * H_ * W_;               // 131072 spatial positions
// d_out float offsets: [0]=loss, [1..32]=input2_KL, [33..33+NTOT)=quantized(BCHW),
// [OFF_ENC .. OFF_ENC+NSP*K)=encodings
constexpr int OFF_Q   = 33;
constexpr int OFF_ENC = OFF_Q + NTOT;            // 8388641 (byte 33554564 == 4 mod 64)
constexpr long long ENC_ELEMS = (long long)NSP * K_;   // 134217728 (2^27)
// (OFF_ENC + 15)*4 == 0 mod 64: fill starts 64B-LINE-aligned.
// Head (row 0, cols 0..14) and tail (last row, col 1023) patched in vq_fin.
constexpr int ENC_HEAD = 15;
constexpr int ENC_N8 = (int)((ENC_ELEMS - ENC_HEAD - 1) / 8);   // 16777214 8-elem groups
constexpr int ENC_BLOCKS = (ENC_N8 + 255) / 256;                // 65536 blocks

constexpr int MAIN_BLOCKS  = NSP / 64;                          // 2048 blocks
constexpr int TOTAL_BLOCKS = MAIN_BLOCKS + ENC_BLOCKS;          // 67584

typedef float v4f __attribute__((ext_vector_type(4)));

// Fused kernel.
//  Blocks [0, MAIN_BLOCKS): quantized+loss; partial loss -> ws[bid] (plain store,
//    no atomic, no memset needed).
//  Blocks [MAIN_BLOCKS, TOTAL_BLOCKS): computed one-hot fill, 32 B per thread
//    (two independent dwordx4 stores -> 2x stores in flight per wave vs R10),
//    block covers exactly 2 rows (8 KB), 3 wave-uniform x_tilde words.
__global__ __launch_bounds__(256) void vq_fused(const float* __restrict__ input1,
                                                const int*   __restrict__ x_tilde,
                                                const float* __restrict__ weight,
                                                float* __restrict__ out,  // d_out base
                                                float* __restrict__ ws) { // d_ws partials
    const int bid = blockIdx.x;
    if (bid >= MAIN_BLOCKS) {
        // ---- encodings fill path ----
        const int eb = bid - MAIN_BLOCKS;
        const int g  = eb * 256 + threadIdx.x;
        if (g >= ENC_N8) return;              // 2 idle threads in the last block
        const int r0 = eb << 1;
        const int t0 = x_tilde[r0];
        const int t1 = x_tilde[r0 + 1];
        const int t2 = x_tilde[(r0 + 2 < NSP) ? r0 + 2 : NSP - 1];
        const int c0 = ENC_HEAD + (threadIdx.x << 3);   // 15..2055, rel. row r0
        v4f va, vb;
        #pragma unroll
        for (int j = 0; j < 8; ++j) {
            const int e   = c0 + j;
            const int sel = e >> 10;                    // 0,1,2: which row
            const int col = e & 1023;
            const int t   = (sel == 0) ? t0 : ((sel == 1) ? t1 : t2);
            const float f = (t == col) ? 1.f : 0.f;
            if (j < 4) ((float*)&va)[j] = f; else ((float*)&vb)[j - 4] = f;
        }
        float* p = out + OFF_ENC + ENC_HEAD + (g << 3); // 32B-aligned
        *reinterpret_cast<v4f*>(p)     = va;
        *reinterpret_cast<v4f*>(p + 4) = vb;
        return;
    }

    // ---- quantized + loss path (transposed gather, 4-way channel split) ----
    const int tid = threadIdx.x;
    const int n   = bid * 64 + (tid & 63);           // [0, NSP)
    const int cq  = tid >> 6;                        // 0..3 -> channels 16cq..16cq+15
    const int b   = n >> 12;                         // H*W = 4096
    const int hw  = n & 4095;
    const int t   = x_tilde[n];
    const float* __restrict__ wrow = weight + (t << 6) + (cq << 4);
    const float* __restrict__ xin  = input1 + (b << 18) + (cq << 16) + hw;
    float* __restrict__ qout = out + OFF_Q + (b << 18) + (cq << 16) + hw;

    const float4 w0 = *reinterpret_cast<const float4*>(wrow);
    const float4 w1 = *reinterpret_cast<const float4*>(wrow + 4);
    const float4 w2 = *reinterpret_cast<const float4*>(wrow + 8);
    const float4 w3 = *reinterpret_cast<const float4*>(wrow + 12);
    const float wv[16] = {w0.x, w0.y, w0.z, w0.w, w1.x, w1.y, w1.z, w1.w,
                          w2.x, w2.y, w2.z, w2.w, w3.x, w3.y, w3.z, w3.w};
    float local = 0.f;
    #pragma unroll
    for (int j = 0; j < 16; ++j) {
        const float x = xin[j << 12];
        const float d = wv[j] - x;
        qout[j << 12] = x + d;       // straight-through: x + (q - x)
        local += d * d;
    }

    // wave64 reduce + one plain store per block (overwrites; no zeroing needed)
    for (int o = 32; o > 0; o >>= 1) local += __shfl_down(local, o);
    __shared__ float sm[4];
    const int lane = tid & 63, wid = tid >> 6;
    if (lane == 0) sm[wid] = local;
    __syncthreads();
    if (tid == 0) {
        ws[bid] = sm[0] + sm[1] + sm[2] + sm[3];
    }
}

// Finalize: reduce the 2048 partial sums -> loss, input2_KL passthrough, and
// the 16 edge elements the line-aligned fill skipped.
__global__ __launch_bounds__(256) void vq_fin(const int* __restrict__ x_tilde,
                                              const float* __restrict__ ws,
                                              const float* __restrict__ kl,
                                              float* __restrict__ out) {
    const int tid = threadIdx.x;
    float local = 0.f;
    #pragma unroll
    for (int k = 0; k < 8; ++k) local += ws[tid + (k << 8)];
    for (int o = 32; o > 0; o >>= 1) local += __shfl_down(local, o);
    __shared__ float sm[4];
    if ((tid & 63) == 0) sm[tid >> 6] = local;
    __syncthreads();
    if (tid == 0) out[0] = 1.25f * (sm[0] + sm[1] + sm[2] + sm[3]) / (float)NTOT;
    if (tid >= 64 && tid < 96) out[1 + tid - 64] = kl[tid - 64];
    if (tid == 96) {
        const int t0 = x_tilde[0];
        #pragma unroll
        for (int j = 0; j < ENC_HEAD; ++j)
            out[OFF_ENC + j] = (t0 == j) ? 1.f : 0.f;      // row 0, cols 0..14
        const int tl = x_tilde[NSP - 1];
        out[OFF_ENC + (int)ENC_ELEMS - 1] = (tl == 1023) ? 1.f : 0.f;
    }
}

extern "C" void kernel_launch(void* const* d_in, const int* in_sizes, int n_in,
                              void* d_out, int out_size, void* d_ws, size_t ws_size,
                              hipStream_t stream) {
    const float* input1 = (const float*)d_in[0];
    const float* kl     = (const float*)d_in[1];
    const float* weight = (const float*)d_in[2];
    const int*   x_til  = (const int*)d_in[3];
    float* out = (float*)d_out;
    float* ws  = (float*)d_ws;

    vq_fused<<<TOTAL_BLOCKS, 256, 0, stream>>>(input1, x_til, weight, out, ws);
    vq_fin<<<1, 256, 0, stream>>>(x_til, ws, kl, out);
}